// Round 1
// baseline (1713.865 us; speedup 1.0000x reference)
//
#include <hip/hip_runtime.h>
#include <hip/hip_bf16.h>

#define EMB_D 128
#define CHUNK 1024
#define PB    2048   // nodes per block in max pass
#define TILE  16     // nodes per tile in max pass

typedef __hip_bfloat16 bf16;

__global__ void init_out_kernel(float* out, int out_size) {
    int t = threadIdx.x;
    if (t < out_size) out[t] = -INFINITY;
}

// Kernel A: per-chunk sums of gathered embedding rows (all 128 dims)
__global__ void chunk_sums_kernel(const int* __restrict__ tokens,
                                  const float* __restrict__ emb,
                                  float* __restrict__ sumE, int n) {
    __shared__ int toks[CHUNK];
    __shared__ float red[256];
    int c = blockIdx.x;
    int i0 = c * CHUNK;
    int cnt = min(CHUNK, n - i0);
    for (int t = threadIdx.x; t < cnt; t += 256) toks[t] = tokens[i0 + t];
    __syncthreads();
    int d = threadIdx.x & 127;
    int h = threadIdx.x >> 7;   // 2 node-interleaved halves
    float acc = 0.f;
    #pragma unroll 4
    for (int j = h; j < cnt; j += 2)
        acc += emb[(size_t)toks[j] * EMB_D + d];
    red[threadIdx.x] = acc;
    __syncthreads();
    if (threadIdx.x < 128)
        sumE[(size_t)c * EMB_D + threadIdx.x] =
            red[threadIdx.x] + red[threadIdx.x + 128];
}

// Kernel B: sequential exclusive scan over chunk sums (single block)
__global__ void scan_chunks_kernel(const float* __restrict__ sumE,
                                   float* __restrict__ prefE, int C) {
    int d = threadIdx.x;
    float run = 0.f;
    for (int c = 0; c < C; ++c) {
        float v = sumE[(size_t)c * EMB_D + d];
        prefE[(size_t)c * EMB_D + d] = run;
        run += v;
    }
}

// Kernel C: re-gather, running inclusive cumsum, store SE as bf16
__global__ void write_S_kernel(const int* __restrict__ tokens,
                               const float* __restrict__ emb,
                               const float* __restrict__ prefE,
                               bf16* __restrict__ S, int n) {
    __shared__ int toks[CHUNK];
    int c = blockIdx.x;
    int i0 = c * CHUNK;
    int cnt = min(CHUNK, n - i0);
    for (int t = threadIdx.x; t < cnt; t += 128) toks[t] = tokens[i0 + t];
    __syncthreads();
    int d = threadIdx.x;
    float run = prefE[(size_t)c * EMB_D + d];
    #pragma unroll 4
    for (int j = 0; j < cnt; ++j) {
        run += emb[(size_t)toks[j] * EMB_D + d];
        S[(size_t)(i0 + j) * EMB_D + d] = __float2bfloat16(run);
    }
}

__device__ inline void atomicMaxF(float* addr, float v) {
    if (v >= 0.f) atomicMax((int*)addr, __float_as_int(v));
    else          atomicMin((unsigned int*)addr, __float_as_uint(v));
}

// Kernel D: h_i = W*(SE[end_i]-SE[i-1]) + cnt_i*b ; out = max over i
__global__ __launch_bounds__(256, 2) void max_pass_kernel(
        const int* __restrict__ ends, const bf16* __restrict__ S,
        const float* __restrict__ W, const float* __restrict__ bvec,
        float* __restrict__ out, int n) {
    __shared__ float Wt[EMB_D][EMB_D + 1];  // Wt[k][d] = W[d][k], padded
    __shared__ float Etile[TILE][EMB_D];
    __shared__ int   s_end[TILE];
    __shared__ float s_cnt[TILE];
    __shared__ float red[256];
    int tid = threadIdx.x;
    for (int idx = tid; idx < EMB_D * EMB_D; idx += 256) {
        int dd = idx >> 7, kk = idx & 127;
        Wt[kk][dd] = W[idx];   // W[dd][kk]
    }
    int d = tid & 127;
    int g = tid >> 7;          // 0..1
    float bd = bvec[d];
    float mx = -INFINITY;
    int start = blockIdx.x * PB;
    int stop  = min(start + PB, n);
    __syncthreads();
    for (int base = start; base < stop; base += TILE) {
        int m = min(TILE, stop - base);
        if (tid < TILE && tid < m) {
            int e = ends[base + tid];
            s_end[tid] = e;
            s_cnt[tid] = (float)(e - (base + tid) + 1);
        }
        __syncthreads();
        // stage E = SE[end_j] - SE[j-1] for this tile
        for (int j = g; j < m; j += 2) {
            float se = __bfloat162float(S[(size_t)s_end[j] * EMB_D + d]);
            int ip = base + j - 1;
            float sp = (ip >= 0) ? __bfloat162float(S[(size_t)ip * EMB_D + d]) : 0.f;
            Etile[j][d] = se - sp;
        }
        for (int j = m + g; j < TILE; j += 2) Etile[j][d] = 0.f;
        __syncthreads();
        // matvec: group g handles 8 nodes [g*8, g*8+8)
        float a[8];
        #pragma unroll
        for (int i = 0; i < 8; ++i) a[i] = 0.f;
        int jb = g * 8;
        #pragma unroll 4
        for (int k = 0; k < EMB_D; ++k) {
            float w = Wt[k][d];
            #pragma unroll
            for (int i = 0; i < 8; ++i) a[i] += w * Etile[jb + i][k];
        }
        #pragma unroll
        for (int i = 0; i < 8; ++i)
            if (jb + i < m) mx = fmaxf(mx, a[i] + s_cnt[jb + i] * bd);
        __syncthreads();
    }
    red[tid] = mx;
    __syncthreads();
    if (tid < 128) {
        float v = fmaxf(red[tid], red[tid + 128]);
        atomicMaxF(&out[tid], v);
    }
}

extern "C" void kernel_launch(void* const* d_in, const int* in_sizes, int n_in,
                              void* d_out, int out_size, void* d_ws, size_t ws_size,
                              hipStream_t stream) {
    const int*   tokens = (const int*)d_in[0];
    const int*   ends   = (const int*)d_in[1];
    const float* emb    = (const float*)d_in[2];
    const float* W      = (const float*)d_in[3];
    const float* bvec   = (const float*)d_in[4];
    float* out = (float*)d_out;
    int n = in_sizes[0];
    int C = (n + CHUNK - 1) / CHUNK;

    float* sumE  = (float*)d_ws;
    float* prefE = sumE + (size_t)C * EMB_D;
    bf16*  S     = (bf16*)(prefE + (size_t)C * EMB_D);
    // footprint: 2*C*128*4 + n*128*2 bytes  (~257 MB for n=1e6)

    init_out_kernel<<<1, 128, 0, stream>>>(out, out_size);
    chunk_sums_kernel<<<C, 256, 0, stream>>>(tokens, emb, sumE, n);
    scan_chunks_kernel<<<1, 128, 0, stream>>>(sumE, prefE, C);
    write_S_kernel<<<C, 128, 0, stream>>>(tokens, emb, prefE, S, n);
    int NB = (n + PB - 1) / PB;
    max_pass_kernel<<<NB, 256, 0, stream>>>(ends, S, W, bvec, out, n);
}

// Round 3
// 292.283 us; speedup vs baseline: 5.8637x; 5.8637x over previous
//
#include <hip/hip_runtime.h>
#include <hip/hip_bf16.h>

#define D      128
#define LG     9
#define CHUNK  512   // (1 << LG)

typedef __attribute__((ext_vector_type(8))) short          short8;
typedef __attribute__((ext_vector_type(8))) unsigned short ushort8;
typedef __attribute__((ext_vector_type(4))) float          floatx4;

__device__ inline float b2f(unsigned short u) {
    return __uint_as_float(((unsigned)u) << 16);
}
__device__ inline short f2bf(float f) {
    __hip_bfloat16 h = __float2bfloat16(f);
    unsigned short u;
    __builtin_memcpy(&u, &h, 2);
    return (short)u;
}

__global__ void init_out_kernel(float* out, int out_size) {
    int t = threadIdx.x;
    if (t < out_size) out[t] = -INFINITY;
}

// Pass 1: single gather pass. Chunk-LOCAL inclusive cumsum of embedding rows,
// stored bf16; chunk totals to sumE (fp32).
__global__ void local_scan_kernel(const int* __restrict__ tokens,
                                  const float* __restrict__ emb,
                                  unsigned short* __restrict__ S,
                                  float* __restrict__ sumE, int n) {
    __shared__ int toks[CHUNK];
    int c  = blockIdx.x;
    int i0 = c << LG;
    int cnt = min(CHUNK, n - i0);
    for (int t = threadIdx.x; t < cnt; t += 128) toks[t] = tokens[i0 + t];
    __syncthreads();
    int d = threadIdx.x;
    float run = 0.f;
    #pragma unroll 4
    for (int j = 0; j < cnt; ++j) {
        run += emb[(size_t)toks[j] * D + d];
        S[(size_t)(i0 + j) * D + d] = (unsigned short)f2bf(run);
    }
    sumE[(size_t)c * D + d] = run;
}

// Pass 2: in-place exclusive scan of chunk totals (one wave per dim).
__global__ void scan_kernel(float* sumE, int C) {
    int d    = blockIdx.x;     // 0..127
    int lane = threadIdx.x;    // 0..63
    float carry = 0.f;
    for (int c0 = 0; c0 < C; c0 += 64) {
        int c = c0 + lane;
        float v = (c < C) ? sumE[(size_t)c * D + d] : 0.f;
        float incl = v;
        #pragma unroll
        for (int off = 1; off < 64; off <<= 1) {
            float t = __shfl_up(incl, off);
            if (lane >= off) incl += t;
        }
        if (c < C) sumE[(size_t)c * D + d] = carry + incl - v;  // exclusive
        carry += __shfl(incl, 63);
    }
}

__device__ inline void atomicMaxF(float* addr, float v) {
    if (v >= 0.f) atomicMax((int*)addr, __float_as_int(v));
    else          atomicMin((unsigned int*)addr, __float_as_uint(v));
}

// Pass 3: h = W*(S[end]-S[prev]) + cnt*b via MFMA; out = per-dim max.
// Each wave owns a contiguous range of 16-node tiles; full W^T held in regs.
__global__ __launch_bounds__(256, 2) void max_pass_kernel(
        const int* __restrict__ ends, const unsigned short* __restrict__ S,
        const float* __restrict__ prefE, const float* __restrict__ W,
        const float* __restrict__ bvec, float* __restrict__ out,
        int n, int n_tiles, int tpw) {
    __shared__ float red[4][8][16];
    int lane = threadIdx.x & 63;
    int wid  = threadIdx.x >> 6;
    int c  = lane & 15;   // A-row / C-col index
    int kg = lane >> 4;   // k-subgroup 0..3

    // Preload W fragments (bf16) and bias slices.
    short8 Wf[8][4];
    float  bc[8];
    #pragma unroll
    for (int t = 0; t < 8; ++t) {
        const float* wr = W + (size_t)(t * 16 + c) * D + kg * 8;
        bc[t] = bvec[t * 16 + c];
        #pragma unroll
        for (int kk = 0; kk < 4; ++kk) {
            short8 f;
            #pragma unroll
            for (int j = 0; j < 8; ++j) f[j] = f2bf(wr[kk * 32 + j]);
            Wf[t][kk] = f;
        }
    }
    float mx[8];
    #pragma unroll
    for (int t = 0; t < 8; ++t) mx[t] = -INFINITY;

    int gw = blockIdx.x * 4 + wid;
    int t0 = gw * tpw;
    int t1 = min(n_tiles, t0 + tpw);
    for (int tt = t0; tt < t1; ++tt) {
        int base = tt * 16;
        int node = base + c;
        bool vr  = node < n;
        int e  = vr ? ends[node] : 0;
        int p  = node - 1;
        int pc = max(p, 0);
        int ce = e >> LG, cp = pc >> LG;
        bool fast = __all(vr && p >= 0 && ce == cp);
        const ushort8* pe = (const ushort8*)(S + (size_t)e  * D + kg * 8);
        const ushort8* pp = (const ushort8*)(S + (size_t)pc * D + kg * 8);
        short8 A[4];
        if (fast) {
            #pragma unroll
            for (int kk = 0; kk < 4; ++kk) {
                ushort8 se = pe[kk * 4];
                ushort8 sp = pp[kk * 4];
                short8 a;
                #pragma unroll
                for (int j = 0; j < 8; ++j)
                    a[j] = f2bf(b2f(se[j]) - b2f(sp[j]));
                A[kk] = a;
            }
        } else {
            const float* qe = prefE + (size_t)ce * D + kg * 8;
            const float* qp = prefE + (size_t)cp * D + kg * 8;
            float vmask = vr ? 1.f : 0.f;
            float pmask = (p >= 0) ? 1.f : 0.f;
            #pragma unroll
            for (int kk = 0; kk < 4; ++kk) {
                ushort8 se = pe[kk * 4];
                ushort8 sp = pp[kk * 4];
                short8 a;
                #pragma unroll
                for (int j = 0; j < 8; ++j) {
                    float fe = b2f(se[j]) + qe[kk * 32 + j];
                    float fp = b2f(sp[j]) + qp[kk * 32 + j];
                    a[j] = f2bf(vmask * (fe - pmask * fp));
                }
                A[kk] = a;
            }
        }
        floatx4 cnt;
        #pragma unroll
        for (int i = 0; i < 4; ++i) {
            int nd = base + kg * 4 + i;
            cnt[i] = (nd < n) ? (float)(ends[nd] - nd + 1) : 0.f;
        }
        #pragma unroll
        for (int t = 0; t < 8; ++t) {
            floatx4 acc = {0.f, 0.f, 0.f, 0.f};
            #pragma unroll
            for (int kk = 0; kk < 4; ++kk)
                acc = __builtin_amdgcn_mfma_f32_16x16x32_bf16(A[kk], Wf[t][kk], acc, 0, 0, 0);
            #pragma unroll
            for (int i = 0; i < 4; ++i) {
                int nd = base + kg * 4 + i;
                float h = acc[i] + cnt[i] * bc[t];
                if (nd < n) mx[t] = fmaxf(mx[t], h);
            }
        }
    }
    // Reduce across the 4 k-subgroups (they hold the same d = t*16+c).
    #pragma unroll
    for (int t = 0; t < 8; ++t) {
        float v = mx[t];
        v = fmaxf(v, __shfl_xor(v, 16));
        v = fmaxf(v, __shfl_xor(v, 32));
        mx[t] = v;
    }
    if (kg == 0) {
        #pragma unroll
        for (int t = 0; t < 8; ++t) red[wid][t][c] = mx[t];
    }
    __syncthreads();
    if (threadIdx.x < 128) {
        int t = threadIdx.x >> 4, cc = threadIdx.x & 15;
        float v = fmaxf(fmaxf(red[0][t][cc], red[1][t][cc]),
                        fmaxf(red[2][t][cc], red[3][t][cc]));
        atomicMaxF(&out[t * 16 + cc], v);
    }
}

extern "C" void kernel_launch(void* const* d_in, const int* in_sizes, int n_in,
                              void* d_out, int out_size, void* d_ws, size_t ws_size,
                              hipStream_t stream) {
    const int*   tokens = (const int*)d_in[0];
    const int*   ends   = (const int*)d_in[1];
    const float* emb    = (const float*)d_in[2];
    const float* W      = (const float*)d_in[3];
    const float* bvec   = (const float*)d_in[4];
    float* out = (float*)d_out;
    int n = in_sizes[0];
    int C = (n + CHUNK - 1) >> LG;

    unsigned short* S    = (unsigned short*)d_ws;          // n*128 bf16 = 256 MB
    float*          sumE = (float*)(S + (size_t)n * D);    // C*128 fp32 (scanned in place)
    // total = n*256 + C*512 bytes = 257,000,448 for n=1e6 (same as proven R0 footprint)

    init_out_kernel<<<1, 128, 0, stream>>>(out, out_size);
    local_scan_kernel<<<C, 128, 0, stream>>>(tokens, emb, S, sumE, n);
    scan_kernel<<<128, 64, 0, stream>>>(sumE, C);

    int n_tiles = (n + 15) / 16;
    int nblocks = 512;                       // 2048 waves
    int tpw = (n_tiles + 2047) / 2048;
    max_pass_kernel<<<nblocks, 256, 0, stream>>>(ends, S, sumE, W, bvec, out,
                                                 n, n_tiles, tpw);
}